// Round 1
// baseline (1446.754 us; speedup 1.0000x reference)
//
#include <hip/hip_runtime.h>
#include <math.h>

#define EPSBN 1e-3f

__device__ __forceinline__ float hsig(float x) {
    return fminf(fmaxf(0.2f * x + 0.5f, 0.f), 1.f);
}

// ---------------------------------------------------------------------------
// Fold BN0 into w1/b1, BN1 into w2/b2, BN2 into wx/blstm.
// BN: x' = x*s + t, s = g/sqrt(v+eps), t = b - m*s.
// conv(x') = conv_with(w*s[ci]) + const_per_co(sum t[ci]*w)   (VALID conv)
// ---------------------------------------------------------------------------
__global__ void fold_weights(
    const float* __restrict__ bn0g, const float* __restrict__ bn0b,
    const float* __restrict__ bn0m, const float* __restrict__ bn0v,
    const float* __restrict__ w1,   const float* __restrict__ b1,
    const float* __restrict__ bn1g, const float* __restrict__ bn1b,
    const float* __restrict__ bn1m, const float* __restrict__ bn1v,
    const float* __restrict__ w2,   const float* __restrict__ b2,
    const float* __restrict__ bn2g, const float* __restrict__ bn2b,
    const float* __restrict__ bn2m, const float* __restrict__ bn2v,
    const float* __restrict__ wx,   const float* __restrict__ blstm,
    float* __restrict__ w1f, float* __restrict__ b1f,
    float* __restrict__ w2f, float* __restrict__ b2f,
    float* __restrict__ wxf, float* __restrict__ blf)
{
    int idx = blockIdx.x * 256 + threadIdx.x;
    if (idx < 131072) {                       // wxf: [512][256], ci=(k)&31
        int ci = (idx >> 8) & 31;
        float s = bn2g[ci] * rsqrtf(bn2v[ci] + EPSBN);
        wxf[idx] = wx[idx] * s;
    } else if (idx < 132096) {                // w1f: 1024, ci = (i>>4)&3
        int i = idx - 131072;
        int ci = (i >> 4) & 3;
        float s = bn0g[ci] * rsqrtf(bn0v[ci] + EPSBN);
        w1f[i] = w1[i] * s;
    } else if (idx < 136704) {                // w2f: 4608, ci = (i>>5)&15
        int i = idx - 132096;
        int ci = (i >> 5) & 15;
        float s = bn1g[ci] * rsqrtf(bn1v[ci] + EPSBN);
        w2f[i] = w2[i] * s;
    } else if (idx < 136960) {                // blf: 256 (blstm + BN2 shift thru wx)
        int co = idx - 136704;
        float acc = blstm[co];
        for (int k = 0; k < 512; k++) {
            int ci = k & 31;
            float s = bn2g[ci] * rsqrtf(bn2v[ci] + EPSBN);
            float t = bn2b[ci] - bn2m[ci] * s;
            acc = fmaf(t, wx[k * 256 + co], acc);
        }
        blf[co] = acc;
    } else if (idx < 136976) {                // b1f: 16 (b1 + BN0 shift thru w1)
        int co = idx - 136960;
        float acc = b1[co];
        for (int k = 0; k < 64; k++) {
            int ci = k & 3;
            float s = bn0g[ci] * rsqrtf(bn0v[ci] + EPSBN);
            float t = bn0b[ci] - bn0m[ci] * s;
            acc = fmaf(t, w1[k * 16 + co], acc);
        }
        b1f[co] = acc;
    } else if (idx < 137008) {                // b2f: 32 (b2 + BN1 shift thru w2)
        int co = idx - 136976;
        float acc = b2[co];
        for (int k = 0; k < 144; k++) {
            int ci = k & 15;
            float s = bn1g[ci] * rsqrtf(bn1v[ci] + EPSBN);
            float t = bn1b[ci] - bn1m[ci] * s;
            acc = fmaf(t, w2[k * 32 + co], acc);
        }
        b2f[co] = acc;
    }
}

// ---------------------------------------------------------------------------
// conv1: [384,64,64,4] -> [384,31,31,16], 4x4 stride 2 VALID, relu
// ---------------------------------------------------------------------------
__global__ void conv1_k(const float* __restrict__ in,
                        const float* __restrict__ w1f,
                        const float* __restrict__ b1f,
                        float* __restrict__ out)
{
    int idx = blockIdx.x * 256 + threadIdx.x;
    if (idx >= 384 * 31 * 31 * 16) return;
    int co = idx & 15;
    int t = idx >> 4;
    int ox = t % 31; t /= 31;
    int oy = t % 31; int n = t / 31;
    float acc = b1f[co];
    #pragma unroll
    for (int kh = 0; kh < 4; kh++) {
        int iy = oy * 2 + kh;
        #pragma unroll
        for (int kw = 0; kw < 4; kw++) {
            int ix = ox * 2 + kw;
            float4 v = *reinterpret_cast<const float4*>(
                &in[((size_t)(n * 64 + iy) * 64 + ix) * 4]);
            const float* wp = &w1f[((kh * 4 + kw) * 4) * 16 + co];
            acc = fmaf(v.x, wp[0],  acc);
            acc = fmaf(v.y, wp[16], acc);
            acc = fmaf(v.z, wp[32], acc);
            acc = fmaf(v.w, wp[48], acc);
        }
    }
    out[idx] = fmaxf(acc, 0.f);
}

// ---------------------------------------------------------------------------
// conv2: [384,31,31,16] -> [384,15,15,32], 3x3 stride 2 VALID, relu
// ---------------------------------------------------------------------------
__global__ void conv2_k(const float* __restrict__ in,
                        const float* __restrict__ w2f,
                        const float* __restrict__ b2f,
                        float* __restrict__ out)
{
    int idx = blockIdx.x * 256 + threadIdx.x;
    if (idx >= 384 * 15 * 15 * 32) return;
    int co = idx & 31;
    int t = idx >> 5;
    int ox = t % 15; t /= 15;
    int oy = t % 15; int n = t / 15;
    float acc = b2f[co];
    #pragma unroll
    for (int kh = 0; kh < 3; kh++) {
        int iy = oy * 2 + kh;
        #pragma unroll
        for (int kw = 0; kw < 3; kw++) {
            int ix = ox * 2 + kw;
            const float* ip = &in[((size_t)(n * 31 + iy) * 31 + ix) * 16];
            const float* wp = &w2f[((kh * 3 + kw) * 16) * 32 + co];
            #pragma unroll
            for (int c4 = 0; c4 < 4; c4++) {
                float4 v = *reinterpret_cast<const float4*>(ip + c4 * 4);
                acc = fmaf(v.x, wp[(c4 * 4 + 0) * 32], acc);
                acc = fmaf(v.y, wp[(c4 * 4 + 1) * 32], acc);
                acc = fmaf(v.z, wp[(c4 * 4 + 2) * 32], acc);
                acc = fmaf(v.w, wp[(c4 * 4 + 3) * 32], acc);
            }
        }
    }
    out[idx] = fmaxf(acc, 0.f);
}

// ---------------------------------------------------------------------------
// x-conv: [384,15,15,32] -> zx [384,144,256], 4x4 VALID stride 1.
// Implicit GEMM: M=384*144, K=512, N=256. Block: 8 M-rows x 256 co.
// bias (blstm + BN2 shift) folded in here.
// ---------------------------------------------------------------------------
#define XMB 8
__global__ void xconv_k(const float* __restrict__ act2,
                        const float* __restrict__ wxf,
                        const float* __restrict__ blf,
                        float* __restrict__ zx)
{
    __shared__ float patch[XMB][512];
    int tid = threadIdx.x;
    int m0 = blockIdx.x * XMB;   // 144 % 8 == 0 -> never straddles n
    for (int idx = tid; idx < XMB * 512; idx += 256) {
        int mi = idx >> 9;
        int k = idx & 511;            // k = kh*128 + kw*32 + ci
        int m = m0 + mi;
        int n = m / 144, pos = m % 144;
        int oy = pos / 12, ox = pos % 12;
        int kh = k >> 7;
        int kw = (k >> 5) & 3;
        int ci = k & 31;
        int iy = oy + kh, ix = ox + kw;
        patch[mi][k] = act2[((size_t)(n * 15 + iy) * 15 + ix) * 32 + ci];
    }
    __syncthreads();
    int co = tid;
    float bias = blf[co];
    float acc[XMB];
    #pragma unroll
    for (int mi = 0; mi < XMB; mi++) acc[mi] = bias;
    for (int k = 0; k < 512; k += 4) {
        float w0 = wxf[(k + 0) * 256 + co];
        float w1 = wxf[(k + 1) * 256 + co];
        float w2 = wxf[(k + 2) * 256 + co];
        float w3 = wxf[(k + 3) * 256 + co];
        #pragma unroll
        for (int mi = 0; mi < XMB; mi++) {
            float4 p = *reinterpret_cast<const float4*>(&patch[mi][k]);
            acc[mi] = fmaf(p.x, w0, acc[mi]);
            acc[mi] = fmaf(p.y, w1, acc[mi]);
            acc[mi] = fmaf(p.z, w2, acc[mi]);
            acc[mi] = fmaf(p.w, w3, acc[mi]);
        }
    }
    #pragma unroll
    for (int mi = 0; mi < XMB; mi++)
        zx[(size_t)(m0 + mi) * 256 + co] = acc[mi];
}

// ---------------------------------------------------------------------------
// One ConvLSTM step. h_{t-1} is read from `stacked` slot t-1 (h lives there
// anyway for the final concat); c updated in place (pointwise). t==0: h=c=0.
// h-conv: 4x4 SAME (pad lo=1, hi=2), Cin=64, Cout=256.
// ---------------------------------------------------------------------------
#define LMB 8
__global__ void lstm_step_k(const float* __restrict__ zx,    // [384,144,256]
                            const float* __restrict__ wh,    // [1024,256]
                            float* __restrict__ stacked,     // [4608,768]
                            float* __restrict__ cbuf,        // [4608,64]
                            int t)
{
    __shared__ float patch[LMB][1024];
    __shared__ float zsh[LMB][256];
    int tid = threadIdx.x;
    int m0 = blockIdx.x * LMB;

    if (t > 0) {
        for (int idx = tid; idx < LMB * 1024; idx += 256) {
            int mi = idx >> 10;
            int k = idx & 1023;          // k = kh*256 + kw*64 + ci
            int m = m0 + mi;
            int b = m / 144, pos = m % 144;
            int oy = pos / 12, ox = pos % 12;
            int kh = k >> 8;
            int kw = (k >> 6) & 3;
            int ci = k & 63;
            int iy = oy + kh - 1, ix = ox + kw - 1;
            float v = 0.f;
            if (iy >= 0 && iy < 12 && ix >= 0 && ix < 12)
                v = stacked[(size_t)(b * 144 + iy * 12 + ix) * 768 + (t - 1) * 64 + ci];
            patch[mi][k] = v;
        }
        __syncthreads();
    }

    int co = tid;
    float acc[LMB];
    #pragma unroll
    for (int mi = 0; mi < LMB; mi++) {
        int m = m0 + mi;
        int b = m / 144, pos = m % 144;
        acc[mi] = zx[((size_t)(b * 12 + t) * 144 + pos) * 256 + co];
    }
    if (t > 0) {
        for (int k = 0; k < 1024; k += 4) {
            float w0 = wh[(k + 0) * 256 + co];
            float w1 = wh[(k + 1) * 256 + co];
            float w2 = wh[(k + 2) * 256 + co];
            float w3 = wh[(k + 3) * 256 + co];
            #pragma unroll
            for (int mi = 0; mi < LMB; mi++) {
                float4 p = *reinterpret_cast<const float4*>(&patch[mi][k]);
                acc[mi] = fmaf(p.x, w0, acc[mi]);
                acc[mi] = fmaf(p.y, w1, acc[mi]);
                acc[mi] = fmaf(p.z, w2, acc[mi]);
                acc[mi] = fmaf(p.w, w3, acc[mi]);
            }
        }
        __syncthreads();   // patch reuse barrier before zsh write is not needed,
                           // but keep ordering simple: all MACs done.
    }
    #pragma unroll
    for (int mi = 0; mi < LMB; mi++) zsh[mi][co] = acc[mi];
    __syncthreads();

    // gate update: LMB*64 = 512 cells, 256 threads -> 2 each
    for (int idx = tid; idx < LMB * 64; idx += 256) {
        int mi = idx >> 6;
        int cc = idx & 63;
        int m = m0 + mi;
        float zi = zsh[mi][cc];
        float zf = zsh[mi][64 + cc];
        float zg = zsh[mi][128 + cc];
        float zo = zsh[mi][192 + cc];
        size_t cidx = (size_t)m * 64 + cc;
        float c = (t == 0) ? 0.f : cbuf[cidx];
        c = hsig(zf) * c + hsig(zi) * tanhf(zg);
        float h = hsig(zo) * tanhf(c);
        cbuf[cidx] = c;
        stacked[(size_t)m * 768 + t * 64 + cc] = h;
    }
}

// ---------------------------------------------------------------------------
// comp = relu(stacked[4608,768] @ wo[768,64] + bo)
// ---------------------------------------------------------------------------
__global__ void compconv_k(const float* __restrict__ stacked,
                           const float* __restrict__ wo,
                           const float* __restrict__ bo,
                           float* __restrict__ comp)
{
    int idx = blockIdx.x * 256 + threadIdx.x;
    if (idx >= 4608 * 64) return;
    int co = idx & 63;
    int m = idx >> 6;
    const float* sp = &stacked[(size_t)m * 768];
    float acc = bo[co];
    for (int k = 0; k < 768; k++)
        acc = fmaf(sp[k], wo[k * 64 + co], acc);
    comp[idx] = fmaxf(acc, 0.f);
}

// ---------------------------------------------------------------------------
// dense1: hdn = relu(comp[32,9216] @ wd1[9216,128] + bd1); one wave per output
// ---------------------------------------------------------------------------
__global__ void dense1_k(const float* __restrict__ comp,
                         const float* __restrict__ wd1,
                         const float* __restrict__ bd1,
                         float* __restrict__ hdn)
{
    int gid = blockIdx.x * 256 + threadIdx.x;
    int wave = gid >> 6;            // 0..4095
    int lane = threadIdx.x & 63;
    int r = wave >> 7;              // row 0..31
    int j = wave & 127;             // col 0..127
    const float* cp = &comp[(size_t)r * 9216];
    float acc = 0.f;
    for (int k = lane; k < 9216; k += 64)
        acc = fmaf(cp[k], wd1[(size_t)k * 128 + j], acc);
    #pragma unroll
    for (int off = 32; off; off >>= 1) acc += __shfl_down(acc, off);
    if (lane == 0) hdn[r * 128 + j] = fmaxf(acc + bd1[j], 0.f);
}

// ---------------------------------------------------------------------------
// dense2 + softmax: [32,128] @ [128,2] -> softmax -> out [32,2]
// ---------------------------------------------------------------------------
__global__ void dense2_k(const float* __restrict__ hdn,
                         const float* __restrict__ wd2,
                         const float* __restrict__ bd2,
                         float* __restrict__ out)
{
    int r = threadIdx.x;
    if (r >= 32) return;
    float l0 = bd2[0], l1 = bd2[1];
    for (int k = 0; k < 128; k++) {
        float h = hdn[r * 128 + k];
        l0 = fmaf(h, wd2[k * 2 + 0], l0);
        l1 = fmaf(h, wd2[k * 2 + 1], l1);
    }
    float mx = fmaxf(l0, l1);
    float e0 = expf(l0 - mx), e1 = expf(l1 - mx);
    float s = e0 + e1;
    out[r * 2 + 0] = e0 / s;
    out[r * 2 + 1] = e1 / s;
}

// ---------------------------------------------------------------------------

extern "C" void kernel_launch(void* const* d_in, const int* in_sizes, int n_in,
                              void* d_out, int out_size, void* d_ws, size_t ws_size,
                              hipStream_t stream)
{
    const float* img   = (const float*)d_in[0];
    const float* bn0g  = (const float*)d_in[1];
    const float* bn0b  = (const float*)d_in[2];
    const float* bn0m  = (const float*)d_in[3];
    const float* bn0v  = (const float*)d_in[4];
    const float* w1    = (const float*)d_in[5];
    const float* b1    = (const float*)d_in[6];
    const float* bn1g  = (const float*)d_in[7];
    const float* bn1b  = (const float*)d_in[8];
    const float* bn1m  = (const float*)d_in[9];
    const float* bn1v  = (const float*)d_in[10];
    const float* w2    = (const float*)d_in[11];
    const float* b2    = (const float*)d_in[12];
    const float* bn2g  = (const float*)d_in[13];
    const float* bn2b  = (const float*)d_in[14];
    const float* bn2m  = (const float*)d_in[15];
    const float* bn2v  = (const float*)d_in[16];
    const float* wx    = (const float*)d_in[17];
    const float* wh    = (const float*)d_in[18];
    const float* blstm = (const float*)d_in[19];
    const float* wo    = (const float*)d_in[20];
    const float* bo    = (const float*)d_in[21];
    const float* wd1   = (const float*)d_in[22];
    const float* bd1   = (const float*)d_in[23];
    const float* wd2   = (const float*)d_in[24];
    const float* bd2   = (const float*)d_in[25];
    float* out = (float*)d_out;

    float* ws = (float*)d_ws;
    size_t o = 0;
    float* w1f     = ws + o; o += 1024;
    float* b1f     = ws + o; o += 16;
    float* w2f     = ws + o; o += 4608;
    float* b2f     = ws + o; o += 32;
    float* wxf     = ws + o; o += 131072;
    float* blf     = ws + o; o += 256;       // 137008
    float* act2    = ws + o; o += 2764800;   // [384,15,15,32]
    float* stacked = ws + o; o += 3538944;   // [4608,768] (t*64+c)
    float* cbuf    = ws + o; o += 294912;    // [4608,64]
    float* comp    = ws + o; o += 294912;
    float* hdn     = ws + o; o += 4096;
    float* act1    = ws + o;                 // union: act1 [384,31,31,16]
    float* zx      = ws + o; o += 14155776;  // zx [384,144,256] overwrites act1

    fold_weights<<<(137008 + 255) / 256, 256, 0, stream>>>(
        bn0g, bn0b, bn0m, bn0v, w1, b1,
        bn1g, bn1b, bn1m, bn1v, w2, b2,
        bn2g, bn2b, bn2m, bn2v, wx, blstm,
        w1f, b1f, w2f, b2f, wxf, blf);

    conv1_k<<<(384 * 31 * 31 * 16) / 256, 256, 0, stream>>>(img, w1f, b1f, act1);
    conv2_k<<<(384 * 15 * 15 * 32) / 256, 256, 0, stream>>>(act1, w2f, b2f, act2);
    xconv_k<<<(384 * 144) / XMB, 256, 0, stream>>>(act2, wxf, blf, zx);

    for (int t = 0; t < 12; t++)
        lstm_step_k<<<(32 * 144) / LMB, 256, 0, stream>>>(zx, wh, stacked, cbuf, t);

    compconv_k<<<(4608 * 64) / 256, 256, 0, stream>>>(stacked, wo, bo, comp);
    dense1_k<<<(32 * 128 * 64) / 256, 256, 0, stream>>>(comp, wd1, bd1, hdn);
    dense2_k<<<1, 64, 0, stream>>>(hdn, wd2, bd2, out);
}

// Round 2
// 524.085 us; speedup vs baseline: 2.7605x; 2.7605x over previous
//
#include <hip/hip_runtime.h>
#include <hip/hip_bf16.h>
#include <math.h>

#define EPSBN 1e-3f

typedef __bf16 v8bf __attribute__((ext_vector_type(8)));
typedef float f32x4 __attribute__((ext_vector_type(4)));

__device__ __forceinline__ float hsig(float x) {
    return fminf(fmaxf(0.2f * x + 0.5f, 0.f), 1.f);
}

// ---------------------------------------------------------------------------
// Fold BNs + pack MFMA-fragment-ordered bf16 weights.
// whP[g][ks][l][j]  (g:16 col-groups, ks:32 k-steps, l:64 lanes, j:8)
//   = wh[k*256+co], co=g*16+(l&15), k=ks*32+(l>>4)*8+j
// wxfP[g][ks][l][j] (ks:16) = wx[k*256+co]*s_bn2(ci), ci=k&31
// ---------------------------------------------------------------------------
__global__ void fold_weights(
    const float* __restrict__ bn0g, const float* __restrict__ bn0b,
    const float* __restrict__ bn0m, const float* __restrict__ bn0v,
    const float* __restrict__ w1,   const float* __restrict__ b1,
    const float* __restrict__ bn1g, const float* __restrict__ bn1b,
    const float* __restrict__ bn1m, const float* __restrict__ bn1v,
    const float* __restrict__ w2,   const float* __restrict__ b2,
    const float* __restrict__ bn2g, const float* __restrict__ bn2b,
    const float* __restrict__ bn2m, const float* __restrict__ bn2v,
    const float* __restrict__ wx,   const float* __restrict__ wh,
    const float* __restrict__ blstm,
    float* __restrict__ w1f, float* __restrict__ b1f,
    float* __restrict__ w2f, float* __restrict__ b2f,
    __hip_bfloat16* __restrict__ wxfP, __hip_bfloat16* __restrict__ whP,
    float* __restrict__ blf)
{
    int idx = blockIdx.x * 256 + threadIdx.x;
    if (idx < 262144) {                       // whP
        int j = idx & 7, l = (idx >> 3) & 63, ks = (idx >> 9) & 31, g = idx >> 14;
        int co = g * 16 + (l & 15);
        int k  = ks * 32 + (l >> 4) * 8 + j;
        whP[idx] = __float2bfloat16(wh[k * 256 + co]);
    } else if (idx < 393216) {                // wxfP
        int i = idx - 262144;
        int j = i & 7, l = (i >> 3) & 63, ks = (i >> 9) & 15, g = i >> 13;
        int co = g * 16 + (l & 15);
        int k  = ks * 32 + (l >> 4) * 8 + j;
        int ci = k & 31;
        float s = bn2g[ci] * rsqrtf(bn2v[ci] + EPSBN);
        wxfP[i] = __float2bfloat16(wx[k * 256 + co] * s);
    } else if (idx < 394240) {                // w1f: 1024, ci = (i>>4)&3
        int i = idx - 393216;
        int ci = (i >> 4) & 3;
        float s = bn0g[ci] * rsqrtf(bn0v[ci] + EPSBN);
        w1f[i] = w1[i] * s;
    } else if (idx < 398848) {                // w2f: 4608, ci = (i>>5)&15
        int i = idx - 394240;
        int ci = (i >> 5) & 15;
        float s = bn1g[ci] * rsqrtf(bn1v[ci] + EPSBN);
        w2f[i] = w2[i] * s;
    } else if (idx < 399104) {                // blf: 256 (blstm + BN2 shift thru wx)
        int co = idx - 398848;
        float acc = blstm[co];
        for (int k = 0; k < 512; k++) {
            int ci = k & 31;
            float s = bn2g[ci] * rsqrtf(bn2v[ci] + EPSBN);
            float t = bn2b[ci] - bn2m[ci] * s;
            acc = fmaf(t, wx[k * 256 + co], acc);
        }
        blf[co] = acc;
    } else if (idx < 399120) {                // b1f: 16
        int co = idx - 399104;
        float acc = b1[co];
        for (int k = 0; k < 64; k++) {
            int ci = k & 3;
            float s = bn0g[ci] * rsqrtf(bn0v[ci] + EPSBN);
            float t = bn0b[ci] - bn0m[ci] * s;
            acc = fmaf(t, w1[k * 16 + co], acc);
        }
        b1f[co] = acc;
    } else if (idx < 399152) {                // b2f: 32
        int co = idx - 399120;
        float acc = b2[co];
        for (int k = 0; k < 144; k++) {
            int ci = k & 15;
            float s = bn1g[ci] * rsqrtf(bn1v[ci] + EPSBN);
            float t = bn1b[ci] - bn1m[ci] * s;
            acc = fmaf(t, w2[k * 32 + co], acc);
        }
        b2f[co] = acc;
    }
}

// ---------------------------------------------------------------------------
// conv1: [384,64,64,4] -> [384,31,31,16] f32, 4x4 s2 VALID, relu
// ---------------------------------------------------------------------------
__global__ void conv1_k(const float* __restrict__ in,
                        const float* __restrict__ w1f,
                        const float* __restrict__ b1f,
                        float* __restrict__ out)
{
    int idx = blockIdx.x * 256 + threadIdx.x;
    if (idx >= 384 * 31 * 31 * 16) return;
    int co = idx & 15;
    int t = idx >> 4;
    int ox = t % 31; t /= 31;
    int oy = t % 31; int n = t / 31;
    float acc = b1f[co];
    #pragma unroll
    for (int kh = 0; kh < 4; kh++) {
        int iy = oy * 2 + kh;
        #pragma unroll
        for (int kw = 0; kw < 4; kw++) {
            int ix = ox * 2 + kw;
            float4 v = *reinterpret_cast<const float4*>(
                &in[((size_t)(n * 64 + iy) * 64 + ix) * 4]);
            const float* wp = &w1f[((kh * 4 + kw) * 4) * 16 + co];
            acc = fmaf(v.x, wp[0],  acc);
            acc = fmaf(v.y, wp[16], acc);
            acc = fmaf(v.z, wp[32], acc);
            acc = fmaf(v.w, wp[48], acc);
        }
    }
    out[idx] = fmaxf(acc, 0.f);
}

// ---------------------------------------------------------------------------
// conv2: [384,31,31,16] f32 -> [384,15,15,32] bf16, 3x3 s2 VALID, relu
// ---------------------------------------------------------------------------
__global__ void conv2_k(const float* __restrict__ in,
                        const float* __restrict__ w2f,
                        const float* __restrict__ b2f,
                        __hip_bfloat16* __restrict__ out)
{
    int idx = blockIdx.x * 256 + threadIdx.x;
    if (idx >= 384 * 15 * 15 * 32) return;
    int co = idx & 31;
    int t = idx >> 5;
    int ox = t % 15; t /= 15;
    int oy = t % 15; int n = t / 15;
    float acc = b2f[co];
    #pragma unroll
    for (int kh = 0; kh < 3; kh++) {
        int iy = oy * 2 + kh;
        #pragma unroll
        for (int kw = 0; kw < 3; kw++) {
            int ix = ox * 2 + kw;
            const float* ip = &in[((size_t)(n * 31 + iy) * 31 + ix) * 16];
            const float* wp = &w2f[((kh * 3 + kw) * 16) * 32 + co];
            #pragma unroll
            for (int c4 = 0; c4 < 4; c4++) {
                float4 v = *reinterpret_cast<const float4*>(ip + c4 * 4);
                acc = fmaf(v.x, wp[(c4 * 4 + 0) * 32], acc);
                acc = fmaf(v.y, wp[(c4 * 4 + 1) * 32], acc);
                acc = fmaf(v.z, wp[(c4 * 4 + 2) * 32], acc);
                acc = fmaf(v.w, wp[(c4 * 4 + 3) * 32], acc);
            }
        }
    }
    out[idx] = __float2bfloat16(fmaxf(acc, 0.f));
}

// ---------------------------------------------------------------------------
// x-conv MFMA: act2 bf16 [384,15,15,32] -> zx f32 [384,144,256]
// GEMM M=55296 K=512 N=256. Block: BM=64 rows, 4 waves x 64 cols.
// LDS im2col tile XOR-swizzled ((r&7)<<4) for conflict-free ds_read_b128.
// ---------------------------------------------------------------------------
#define XBM 64
__global__ __launch_bounds__(256, 2) void xconv_mfma(
    const __hip_bfloat16* __restrict__ act2,
    const __hip_bfloat16* __restrict__ wxfP,
    const float* __restrict__ blf,
    float* __restrict__ zx)
{
    __shared__ __align__(16) unsigned char smem[XBM * 1024];
    const int tid = threadIdx.x;
    const int l = tid & 63, w = tid >> 6;
    const int cl = l & 15, q = l >> 4;
    const int m0 = blockIdx.x * XBM;

    // stage: each wave 16 rows, one row per iter (64 lanes x 16B = 1KB row)
    for (int i = 0; i < 16; i++) {
        int r = w * 16 + i;
        int m = m0 + r;
        int n = m / 144, pos = m % 144;
        int oy = pos / 12, ox = pos % 12;
        int iy = oy + q;
        size_t ga = ((size_t)(n * 15 + iy) * 15 + ox) * 32 + cl * 8;
        uint4 v = *reinterpret_cast<const uint4*>(&act2[ga]);
        int byte = r * 1024 + ((l * 16) ^ ((r & 7) << 4));
        *reinterpret_cast<uint4*>(&smem[byte]) = v;
    }
    __syncthreads();

    f32x4 acc[4][4];
    #pragma unroll
    for (int mi = 0; mi < 4; mi++)
        #pragma unroll
        for (int nj = 0; nj < 4; nj++)
            acc[mi][nj] = (f32x4){0.f, 0.f, 0.f, 0.f};

    for (int ks = 0; ks < 16; ks++) {
        v8bf a[4], b[4];
        #pragma unroll
        for (int mi = 0; mi < 4; mi++) {
            int row = mi * 16 + cl;
            int byte = row * 1024 + (((ks * 64 + q * 16)) ^ ((row & 7) << 4));
            a[mi] = *reinterpret_cast<const v8bf*>(&smem[byte]);
        }
        #pragma unroll
        for (int nj = 0; nj < 4; nj++) {
            int g = w * 4 + nj;
            b[nj] = *reinterpret_cast<const v8bf*>(&wxfP[(size_t)((g * 16 + ks) * 64 + l) * 8]);
        }
        #pragma unroll
        for (int mi = 0; mi < 4; mi++)
            #pragma unroll
            for (int nj = 0; nj < 4; nj++)
                acc[mi][nj] = __builtin_amdgcn_mfma_f32_16x16x32_bf16(
                    a[mi], b[nj], acc[mi][nj], 0, 0, 0);
    }

    #pragma unroll
    for (int nj = 0; nj < 4; nj++) {
        int c = w * 64 + nj * 16 + cl;
        float bias = blf[c];
        #pragma unroll
        for (int mi = 0; mi < 4; mi++) {
            #pragma unroll
            for (int reg = 0; reg < 4; reg++) {
                int m = m0 + mi * 16 + q * 4 + reg;
                zx[(size_t)m * 256 + c] = acc[mi][nj][reg] + bias;
            }
        }
    }
}

// ---------------------------------------------------------------------------
// LSTM step MFMA: z = zx[.,t,.,.] + hconv(h_{t-1});  gates -> h,c
// GEMM M=4608 K=1024 N=256. Block: BM=32 rows, 4 waves x 64 cols.
// h_{t-1} gathered bf16 from stacked slot t-1 (SAME pad lo=1,hi=2).
// ---------------------------------------------------------------------------
#define LBM 32
__global__ __launch_bounds__(256, 2) void lstm_mfma(
    const float* __restrict__ zx,              // [384,144,256] f32
    const __hip_bfloat16* __restrict__ whP,
    __hip_bfloat16* __restrict__ stacked,      // [4608,768]
    float* __restrict__ cbuf,                  // [4608,64]
    int t)
{
    __shared__ __align__(16) unsigned char smem[LBM * 2048];  // 64KB; zsh overlays
    const int tid = threadIdx.x;
    const int l = tid & 63, w = tid >> 6;
    const int cl = l & 15, q = l >> 4;
    const int m0 = blockIdx.x * LBM;

    if (t > 0) {
        for (int i = 0; i < 8; i++) {          // 8 rows per wave
            int r = w * 8 + i;
            int m = m0 + r;
            int b = m / 144, pos = m % 144;
            int oy = pos / 12, ox = pos % 12;
            #pragma unroll
            for (int p = 0; p < 2; p++) {
                int e = p * 64 + l;            // 0..127 -> k = e*8
                int kh = e >> 5, kw = (e >> 3) & 3, c8 = e & 7;
                int iy = oy + kh - 1, ix = ox + kw - 1;
                uint4 v = {0u, 0u, 0u, 0u};
                if ((unsigned)iy < 12u && (unsigned)ix < 12u)
                    v = *reinterpret_cast<const uint4*>(
                        &stacked[(size_t)(b * 144 + iy * 12 + ix) * 768 + (t - 1) * 64 + c8 * 8]);
                int byte = r * 2048 + ((e * 16) ^ ((r & 7) << 4));
                *reinterpret_cast<uint4*>(&smem[byte]) = v;
            }
        }
        __syncthreads();
    }

    f32x4 acc[2][4];
    #pragma unroll
    for (int mi = 0; mi < 2; mi++) {
        #pragma unroll
        for (int reg = 0; reg < 4; reg++) {
            int m = m0 + mi * 16 + q * 4 + reg;
            int b = m / 144, pos = m % 144;
            size_t zbase = ((size_t)(b * 12 + t) * 144 + pos) * 256;
            #pragma unroll
            for (int nj = 0; nj < 4; nj++)
                acc[mi][nj][reg] = zx[zbase + w * 64 + nj * 16 + cl];
        }
    }

    if (t > 0) {
        for (int ks = 0; ks < 32; ks++) {
            v8bf a[2], bb[4];
            #pragma unroll
            for (int mi = 0; mi < 2; mi++) {
                int row = mi * 16 + cl;
                int byte = row * 2048 + (((ks * 64 + q * 16)) ^ ((row & 7) << 4));
                a[mi] = *reinterpret_cast<const v8bf*>(&smem[byte]);
            }
            #pragma unroll
            for (int nj = 0; nj < 4; nj++) {
                int g = w * 4 + nj;
                bb[nj] = *reinterpret_cast<const v8bf*>(&whP[(size_t)((g * 32 + ks) * 64 + l) * 8]);
            }
            #pragma unroll
            for (int mi = 0; mi < 2; mi++)
                #pragma unroll
                for (int nj = 0; nj < 4; nj++)
                    acc[mi][nj] = __builtin_amdgcn_mfma_f32_16x16x32_bf16(
                        a[mi], bb[nj], acc[mi][nj], 0, 0, 0);
        }
    }
    __syncthreads();                           // done reading patch LDS

    float* zsh = reinterpret_cast<float*>(smem);   // [32][256] f32 (32KB)
    #pragma unroll
    for (int mi = 0; mi < 2; mi++)
        #pragma unroll
        for (int nj = 0; nj < 4; nj++)
            #pragma unroll
            for (int reg = 0; reg < 4; reg++)
                zsh[(mi * 16 + q * 4 + reg) * 256 + w * 64 + nj * 16 + cl] = acc[mi][nj][reg];
    __syncthreads();

    for (int i = tid; i < LBM * 64; i += 256) {
        int row = i >> 6, cc = i & 63;
        int m = m0 + row;
        float zi = zsh[row * 256 + cc];
        float zf = zsh[row * 256 + 64 + cc];
        float zg = zsh[row * 256 + 128 + cc];
        float zo = zsh[row * 256 + 192 + cc];
        float c = (t == 0) ? 0.f : cbuf[(size_t)m * 64 + cc];
        c = hsig(zf) * c + hsig(zi) * tanhf(zg);
        float h = hsig(zo) * tanhf(c);
        cbuf[(size_t)m * 64 + cc] = c;
        stacked[(size_t)m * 768 + t * 64 + cc] = __float2bfloat16(h);
    }
}

// ---------------------------------------------------------------------------
// comp = relu(stacked[4608,768]bf16 @ wo[768,64] + bo) -> f32
// ---------------------------------------------------------------------------
__global__ void compconv_k(const __hip_bfloat16* __restrict__ stacked,
                           const float* __restrict__ wo,
                           const float* __restrict__ bo,
                           float* __restrict__ comp)
{
    int idx = blockIdx.x * 256 + threadIdx.x;
    if (idx >= 4608 * 64) return;
    int co = idx & 63;
    int m = idx >> 6;
    const __bf16* sp = reinterpret_cast<const __bf16*>(&stacked[(size_t)m * 768]);
    float acc = bo[co];
    for (int k0 = 0; k0 < 768; k0 += 8) {
        v8bf s8 = *reinterpret_cast<const v8bf*>(&sp[k0]);
        #pragma unroll
        for (int j = 0; j < 8; j++)
            acc = fmaf((float)s8[j], wo[(k0 + j) * 64 + co], acc);
    }
    comp[idx] = fmaxf(acc, 0.f);
}

// ---------------------------------------------------------------------------
// dense1: hdn = relu(comp[32,9216] @ wd1[9216,128] + bd1); one wave per output
// ---------------------------------------------------------------------------
__global__ void dense1_k(const float* __restrict__ comp,
                         const float* __restrict__ wd1,
                         const float* __restrict__ bd1,
                         float* __restrict__ hdn)
{
    int gid = blockIdx.x * 256 + threadIdx.x;
    int wave = gid >> 6;
    int lane = threadIdx.x & 63;
    int r = wave >> 7;
    int j = wave & 127;
    const float* cp = &comp[(size_t)r * 9216];
    float acc = 0.f;
    for (int k = lane; k < 9216; k += 64)
        acc = fmaf(cp[k], wd1[(size_t)k * 128 + j], acc);
    #pragma unroll
    for (int off = 32; off; off >>= 1) acc += __shfl_down(acc, off);
    if (lane == 0) hdn[r * 128 + j] = fmaxf(acc + bd1[j], 0.f);
}

// ---------------------------------------------------------------------------
// dense2 + softmax
// ---------------------------------------------------------------------------
__global__ void dense2_k(const float* __restrict__ hdn,
                         const float* __restrict__ wd2,
                         const float* __restrict__ bd2,
                         float* __restrict__ out)
{
    int r = threadIdx.x;
    if (r >= 32) return;
    float l0 = bd2[0], l1 = bd2[1];
    for (int k = 0; k < 128; k++) {
        float h = hdn[r * 128 + k];
        l0 = fmaf(h, wd2[k * 2 + 0], l0);
        l1 = fmaf(h, wd2[k * 2 + 1], l1);
    }
    float mx = fmaxf(l0, l1);
    float e0 = expf(l0 - mx), e1 = expf(l1 - mx);
    float s = e0 + e1;
    out[r * 2 + 0] = e0 / s;
    out[r * 2 + 1] = e1 / s;
}

// ---------------------------------------------------------------------------

extern "C" void kernel_launch(void* const* d_in, const int* in_sizes, int n_in,
                              void* d_out, int out_size, void* d_ws, size_t ws_size,
                              hipStream_t stream)
{
    const float* img   = (const float*)d_in[0];
    const float* bn0g  = (const float*)d_in[1];
    const float* bn0b  = (const float*)d_in[2];
    const float* bn0m  = (const float*)d_in[3];
    const float* bn0v  = (const float*)d_in[4];
    const float* w1    = (const float*)d_in[5];
    const float* b1    = (const float*)d_in[6];
    const float* bn1g  = (const float*)d_in[7];
    const float* bn1b  = (const float*)d_in[8];
    const float* bn1m  = (const float*)d_in[9];
    const float* bn1v  = (const float*)d_in[10];
    const float* w2    = (const float*)d_in[11];
    const float* b2    = (const float*)d_in[12];
    const float* bn2g  = (const float*)d_in[13];
    const float* bn2b  = (const float*)d_in[14];
    const float* bn2m  = (const float*)d_in[15];
    const float* bn2v  = (const float*)d_in[16];
    const float* wx    = (const float*)d_in[17];
    const float* wh    = (const float*)d_in[18];
    const float* blstm = (const float*)d_in[19];
    const float* wo    = (const float*)d_in[20];
    const float* bo    = (const float*)d_in[21];
    const float* wd1   = (const float*)d_in[22];
    const float* bd1   = (const float*)d_in[23];
    const float* wd2   = (const float*)d_in[24];
    const float* bd2   = (const float*)d_in[25];
    float* out = (float*)d_out;

    float* ws = (float*)d_ws;
    size_t o = 0;
    float* w1f = ws + o; o += 1024;
    float* b1f = ws + o; o += 16;
    float* w2f = ws + o; o += 4608;
    float* b2f = ws + o; o += 32;
    float* blf = ws + o; o += 256;
    __hip_bfloat16* wxfP = (__hip_bfloat16*)(ws + o); o += 65536;    // 131072 bf16
    __hip_bfloat16* whP  = (__hip_bfloat16*)(ws + o); o += 131072;   // 262144 bf16
    __hip_bfloat16* act2 = (__hip_bfloat16*)(ws + o); o += 1382400;  // 2764800 bf16
    __hip_bfloat16* stacked = (__hip_bfloat16*)(ws + o); o += 1769472; // 3538944 bf16
    float* cbuf = ws + o; o += 294912;
    float* comp = ws + o; o += 294912;
    float* hdn  = ws + o; o += 4096;
    float* act1 = ws + o;                    // union: act1 [384,31,31,16] f32
    float* zx   = ws + o; o += 14155776;     // zx [384,144,256] f32 (act1 dead by then)

    fold_weights<<<(399152 + 255) / 256, 256, 0, stream>>>(
        bn0g, bn0b, bn0m, bn0v, w1, b1,
        bn1g, bn1b, bn1m, bn1v, w2, b2,
        bn2g, bn2b, bn2m, bn2v, wx, wh, blstm,
        w1f, b1f, w2f, b2f, wxfP, whP, blf);

    conv1_k<<<(384 * 31 * 31 * 16) / 256, 256, 0, stream>>>(img, w1f, b1f, act1);
    conv2_k<<<(384 * 15 * 15 * 32) / 256, 256, 0, stream>>>(act1, w2f, b2f, act2);
    xconv_mfma<<<(384 * 144) / XBM, 256, 0, stream>>>(act2, wxfP, blf, zx);

    for (int t = 0; t < 12; t++)
        lstm_mfma<<<(32 * 144) / LBM, 256, 0, stream>>>(zx, whP, stacked, cbuf, t);

    compconv_k<<<(4608 * 64) / 256, 256, 0, stream>>>(stacked, wo, bo, comp);
    dense1_k<<<(32 * 128 * 64) / 256, 256, 0, stream>>>(comp, wd1, bd1, hdn);
    dense2_k<<<1, 64, 0, stream>>>(hdn, wd2, bd2, out);
}

// Round 3
// 338.149 us; speedup vs baseline: 4.2784x; 1.5499x over previous
//
#include <hip/hip_runtime.h>
#include <hip/hip_bf16.h>
#include <math.h>

#define EPSBN 1e-3f

typedef __bf16 v8bf __attribute__((ext_vector_type(8)));
typedef float f32x4 __attribute__((ext_vector_type(4)));

__device__ __forceinline__ float hsig(float x) {
    return fminf(fmaxf(0.2f * x + 0.5f, 0.f), 1.f);
}

// ---------------------------------------------------------------------------
// Fold BNs + pack MFMA-fragment-ordered bf16 weights.
// P[g][ks][l][j] = W[k][co], co = g*16+(l&15), k = ks*32+(l>>4)*8+j
//   whP:  g 0..15, ks 0..31  (wh 1024x256)
//   wxfP: g 0..15, ks 0..15  (wx 512x256, * BN2 scale)
//   woP:  g 0..3,  ks 0..23  (wo 768x64)
//   wd1P: g 0..7,  ks 0..287 (wd1 9216x128)
// ---------------------------------------------------------------------------
__global__ void fold_weights(
    const float* __restrict__ bn0g, const float* __restrict__ bn0b,
    const float* __restrict__ bn0m, const float* __restrict__ bn0v,
    const float* __restrict__ w1,   const float* __restrict__ b1,
    const float* __restrict__ bn1g, const float* __restrict__ bn1b,
    const float* __restrict__ bn1m, const float* __restrict__ bn1v,
    const float* __restrict__ w2,   const float* __restrict__ b2,
    const float* __restrict__ bn2g, const float* __restrict__ bn2b,
    const float* __restrict__ bn2m, const float* __restrict__ bn2v,
    const float* __restrict__ wx,   const float* __restrict__ wh,
    const float* __restrict__ blstm,
    const float* __restrict__ wo,   const float* __restrict__ wd1,
    float* __restrict__ w1f, float* __restrict__ b1f,
    float* __restrict__ w2f, float* __restrict__ b2f,
    __hip_bfloat16* __restrict__ wxfP, __hip_bfloat16* __restrict__ whP,
    __hip_bfloat16* __restrict__ woP,  __hip_bfloat16* __restrict__ wd1P,
    float* __restrict__ blf)
{
    int idx = blockIdx.x * 256 + threadIdx.x;
    if (idx < 262144) {                       // whP
        int j = idx & 7, l = (idx >> 3) & 63, ks = (idx >> 9) & 31, g = idx >> 14;
        int co = g * 16 + (l & 15);
        int k  = ks * 32 + (l >> 4) * 8 + j;
        whP[idx] = __float2bfloat16(wh[k * 256 + co]);
    } else if (idx < 393216) {                // wxfP
        int i = idx - 262144;
        int j = i & 7, l = (i >> 3) & 63, ks = (i >> 9) & 15, g = i >> 13;
        int co = g * 16 + (l & 15);
        int k  = ks * 32 + (l >> 4) * 8 + j;
        int ci = k & 31;
        float s = bn2g[ci] * rsqrtf(bn2v[ci] + EPSBN);
        wxfP[i] = __float2bfloat16(wx[k * 256 + co] * s);
    } else if (idx < 394240) {                // w1f: 1024, ci = (i>>4)&3
        int i = idx - 393216;
        int ci = (i >> 4) & 3;
        float s = bn0g[ci] * rsqrtf(bn0v[ci] + EPSBN);
        w1f[i] = w1[i] * s;
    } else if (idx < 398848) {                // w2f: 4608, ci = (i>>5)&15
        int i = idx - 394240;
        int ci = (i >> 5) & 15;
        float s = bn1g[ci] * rsqrtf(bn1v[ci] + EPSBN);
        w2f[i] = w2[i] * s;
    } else if (idx < 399104) {                // blf
        int co = idx - 398848;
        float acc = blstm[co];
        for (int k = 0; k < 512; k++) {
            int ci = k & 31;
            float s = bn2g[ci] * rsqrtf(bn2v[ci] + EPSBN);
            float t = bn2b[ci] - bn2m[ci] * s;
            acc = fmaf(t, wx[k * 256 + co], acc);
        }
        blf[co] = acc;
    } else if (idx < 399120) {                // b1f
        int co = idx - 399104;
        float acc = b1[co];
        for (int k = 0; k < 64; k++) {
            int ci = k & 3;
            float s = bn0g[ci] * rsqrtf(bn0v[ci] + EPSBN);
            float t = bn0b[ci] - bn0m[ci] * s;
            acc = fmaf(t, w1[k * 16 + co], acc);
        }
        b1f[co] = acc;
    } else if (idx < 399152) {                // b2f
        int co = idx - 399120;
        float acc = b2[co];
        for (int k = 0; k < 144; k++) {
            int ci = k & 15;
            float s = bn1g[ci] * rsqrtf(bn1v[ci] + EPSBN);
            float t = bn1b[ci] - bn1m[ci] * s;
            acc = fmaf(t, w2[k * 32 + co], acc);
        }
        b2f[co] = acc;
    } else if (idx < 448304) {                // woP: 49152
        int i = idx - 399152;
        int j = i & 7, l = (i >> 3) & 63;
        int rest = i >> 9;                    // 0..95
        int ks = rest % 24, g = rest / 24;
        int co = g * 16 + (l & 15);
        int k  = ks * 32 + (l >> 4) * 8 + j;
        woP[i] = __float2bfloat16(wo[k * 64 + co]);
    } else if (idx < 1627952) {               // wd1P: 1179648
        int i = idx - 448304;
        int j = i & 7, l = (i >> 3) & 63;
        int rest = i >> 9;                    // 0..2303
        int ks = rest % 288, g = rest / 288;
        int col = g * 16 + (l & 15);
        int k   = ks * 32 + (l >> 4) * 8 + j;
        wd1P[i] = __float2bfloat16(wd1[(size_t)k * 128 + col]);
    }
}

// ---------------------------------------------------------------------------
// conv1: [384,64,64,4] -> [384,31,31,16] f32, 4x4 s2 VALID, relu.
// One thread per PIXEL: 16 co accumulators, weights via uniform scalar loads.
// ---------------------------------------------------------------------------
__global__ void conv1_k(const float* __restrict__ in,
                        const float* __restrict__ w1f,
                        const float* __restrict__ b1f,
                        float* __restrict__ out)
{
    int pix = blockIdx.x * 256 + threadIdx.x;
    if (pix >= 384 * 961) return;
    int n = pix / 961, p = pix % 961;
    int oy = p / 31, ox = p % 31;
    float acc[16];
    #pragma unroll
    for (int co = 0; co < 16; co++) acc[co] = b1f[co];
    #pragma unroll
    for (int kh = 0; kh < 4; kh++) {
        const float* row = &in[((size_t)(n * 64 + oy * 2 + kh) * 64 + ox * 2) * 4];
        #pragma unroll
        for (int kw = 0; kw < 4; kw++) {
            float4 v = *reinterpret_cast<const float4*>(row + kw * 4);
            const float* wp = &w1f[(kh * 4 + kw) * 64];
            #pragma unroll
            for (int ci = 0; ci < 4; ci++) {
                float x = (&v.x)[ci];
                #pragma unroll
                for (int co = 0; co < 16; co++)
                    acc[co] = fmaf(x, wp[ci * 16 + co], acc[co]);
            }
        }
    }
    float* op = &out[(size_t)pix * 16];
    #pragma unroll
    for (int c4 = 0; c4 < 4; c4++) {
        float4 s;
        s.x = fmaxf(acc[c4 * 4 + 0], 0.f);
        s.y = fmaxf(acc[c4 * 4 + 1], 0.f);
        s.z = fmaxf(acc[c4 * 4 + 2], 0.f);
        s.w = fmaxf(acc[c4 * 4 + 3], 0.f);
        *reinterpret_cast<float4*>(op + c4 * 4) = s;
    }
}

// ---------------------------------------------------------------------------
// conv2: [384,31,31,16] f32 -> [384,15,15,32] bf16, 3x3 s2 VALID, relu.
// One thread per PIXEL: 32 co accumulators, uniform scalar weights.
// ---------------------------------------------------------------------------
__global__ void conv2_k(const float* __restrict__ in,
                        const float* __restrict__ w2f,
                        const float* __restrict__ b2f,
                        __hip_bfloat16* __restrict__ out)
{
    int pix = blockIdx.x * 256 + threadIdx.x;
    if (pix >= 384 * 225) return;
    int n = pix / 225, p = pix % 225;
    int oy = p / 15, ox = p % 15;
    float acc[32];
    #pragma unroll
    for (int co = 0; co < 32; co++) acc[co] = b2f[co];
    #pragma unroll
    for (int kh = 0; kh < 3; kh++) {
        #pragma unroll
        for (int kw = 0; kw < 3; kw++) {
            const float* ip = &in[((size_t)(n * 31 + oy * 2 + kh) * 31 + ox * 2 + kw) * 16];
            const float* wp = &w2f[(kh * 3 + kw) * 512];
            #pragma unroll
            for (int c4 = 0; c4 < 4; c4++) {
                float4 v = *reinterpret_cast<const float4*>(ip + c4 * 4);
                #pragma unroll
                for (int e = 0; e < 4; e++) {
                    float x = (&v.x)[e];
                    #pragma unroll
                    for (int co = 0; co < 32; co++)
                        acc[co] = fmaf(x, wp[(c4 * 4 + e) * 32 + co], acc[co]);
                }
            }
        }
    }
    __bf16* op = reinterpret_cast<__bf16*>(&out[(size_t)pix * 32]);
    #pragma unroll
    for (int g = 0; g < 4; g++) {
        v8bf s;
        #pragma unroll
        for (int e = 0; e < 8; e++)
            s[e] = (__bf16)fmaxf(acc[g * 8 + e], 0.f);
        *reinterpret_cast<v8bf*>(op + g * 8) = s;
    }
}

// ---------------------------------------------------------------------------
// x-conv MFMA: act2 bf16 [384,15,15,32] -> zx f32 [384,144,256]
// ---------------------------------------------------------------------------
#define XBM 64
__global__ __launch_bounds__(256, 2) void xconv_mfma(
    const __hip_bfloat16* __restrict__ act2,
    const __hip_bfloat16* __restrict__ wxfP,
    const float* __restrict__ blf,
    float* __restrict__ zx)
{
    __shared__ __align__(16) unsigned char smem[XBM * 1024];
    const int tid = threadIdx.x;
    const int l = tid & 63, w = tid >> 6;
    const int cl = l & 15, q = l >> 4;
    const int m0 = blockIdx.x * XBM;

    for (int i = 0; i < 16; i++) {
        int r = w * 16 + i;
        int m = m0 + r;
        int n = m / 144, pos = m % 144;
        int oy = pos / 12, ox = pos % 12;
        int iy = oy + q;
        size_t ga = ((size_t)(n * 15 + iy) * 15 + ox) * 32 + cl * 8;
        uint4 v = *reinterpret_cast<const uint4*>(&act2[ga]);
        int byte = r * 1024 + ((l * 16) ^ ((r & 7) << 4));
        *reinterpret_cast<uint4*>(&smem[byte]) = v;
    }
    __syncthreads();

    f32x4 acc[4][4];
    #pragma unroll
    for (int mi = 0; mi < 4; mi++)
        #pragma unroll
        for (int nj = 0; nj < 4; nj++)
            acc[mi][nj] = (f32x4){0.f, 0.f, 0.f, 0.f};

    for (int ks = 0; ks < 16; ks++) {
        v8bf a[4], b[4];
        #pragma unroll
        for (int mi = 0; mi < 4; mi++) {
            int row = mi * 16 + cl;
            int byte = row * 1024 + (((ks * 64 + q * 16)) ^ ((row & 7) << 4));
            a[mi] = *reinterpret_cast<const v8bf*>(&smem[byte]);
        }
        #pragma unroll
        for (int nj = 0; nj < 4; nj++) {
            int g = w * 4 + nj;
            b[nj] = *reinterpret_cast<const v8bf*>(&wxfP[(size_t)((g * 16 + ks) * 64 + l) * 8]);
        }
        #pragma unroll
        for (int mi = 0; mi < 4; mi++)
            #pragma unroll
            for (int nj = 0; nj < 4; nj++)
                acc[mi][nj] = __builtin_amdgcn_mfma_f32_16x16x32_bf16(
                    a[mi], b[nj], acc[mi][nj], 0, 0, 0);
    }

    #pragma unroll
    for (int nj = 0; nj < 4; nj++) {
        int c = w * 64 + nj * 16 + cl;
        float bias = blf[c];
        #pragma unroll
        for (int mi = 0; mi < 4; mi++) {
            #pragma unroll
            for (int reg = 0; reg < 4; reg++) {
                int m = m0 + mi * 16 + q * 4 + reg;
                zx[(size_t)m * 256 + c] = acc[mi][nj][reg] + bias;
            }
        }
    }
}

// ---------------------------------------------------------------------------
// LSTM step MFMA: BM=16 rows, 4 waves x 64 cols (288 blocks for parallelism).
// ---------------------------------------------------------------------------
#define LBM 16
__global__ __launch_bounds__(256, 2) void lstm_mfma(
    const float* __restrict__ zx,              // [384,144,256] f32
    const __hip_bfloat16* __restrict__ whP,
    __hip_bfloat16* __restrict__ stacked,      // [4608,768] bf16
    float* __restrict__ cbuf,                  // [4608,64]
    int t)
{
    __shared__ __align__(16) unsigned char smem[LBM * 2048];  // 32KB; zsh overlays
    const int tid = threadIdx.x;
    const int l = tid & 63, w = tid >> 6;
    const int cl = l & 15, q = l >> 4;
    const int m0 = blockIdx.x * LBM;

    if (t > 0) {
        for (int i = 0; i < 4; i++) {          // 4 rows per wave
            int r = w * 4 + i;
            int m = m0 + r;
            int b = m / 144, pos = m % 144;
            int oy = pos / 12, ox = pos % 12;
            #pragma unroll
            for (int p = 0; p < 2; p++) {
                int e = p * 64 + l;            // 0..127 -> k = e*8
                int kh = e >> 5, kw = (e >> 3) & 3, c8 = e & 7;
                int iy = oy + kh - 1, ix = ox + kw - 1;
                uint4 v = {0u, 0u, 0u, 0u};
                if ((unsigned)iy < 12u && (unsigned)ix < 12u)
                    v = *reinterpret_cast<const uint4*>(
                        &stacked[(size_t)(b * 144 + iy * 12 + ix) * 768 + (t - 1) * 64 + c8 * 8]);
                int byte = r * 2048 + ((e * 16) ^ ((r & 7) << 4));
                *reinterpret_cast<uint4*>(&smem[byte]) = v;
            }
        }
        __syncthreads();
    }

    f32x4 acc[4];
    #pragma unroll
    for (int reg = 0; reg < 4; reg++) {
        int m = m0 + q * 4 + reg;
        int b = m / 144, pos = m % 144;
        size_t zbase = ((size_t)(b * 12 + t) * 144 + pos) * 256;
        #pragma unroll
        for (int nj = 0; nj < 4; nj++)
            acc[nj][reg] = zx[zbase + w * 64 + nj * 16 + cl];
    }

    if (t > 0) {
        for (int ks = 0; ks < 32; ks++) {
            int row = cl;
            int byte = row * 2048 + (((ks * 64 + q * 16)) ^ ((row & 7) << 4));
            v8bf a = *reinterpret_cast<const v8bf*>(&smem[byte]);
            #pragma unroll
            for (int nj = 0; nj < 4; nj++) {
                int g = w * 4 + nj;
                v8bf bb = *reinterpret_cast<const v8bf*>(&whP[(size_t)((g * 32 + ks) * 64 + l) * 8]);
                acc[nj] = __builtin_amdgcn_mfma_f32_16x16x32_bf16(a, bb, acc[nj], 0, 0, 0);
            }
        }
    }
    __syncthreads();                           // done reading patch LDS

    float* zsh = reinterpret_cast<float*>(smem);   // [16][256] f32 (16KB)
    #pragma unroll
    for (int nj = 0; nj < 4; nj++)
        #pragma unroll
        for (int reg = 0; reg < 4; reg++)
            zsh[(q * 4 + reg) * 256 + w * 64 + nj * 16 + cl] = acc[nj][reg];
    __syncthreads();

    for (int i = tid; i < LBM * 64; i += 256) {
        int row = i >> 6, cc = i & 63;
        int m = m0 + row;
        float zi = zsh[row * 256 + cc];
        float zf = zsh[row * 256 + 64 + cc];
        float zg = zsh[row * 256 + 128 + cc];
        float zo = zsh[row * 256 + 192 + cc];
        float c = (t == 0) ? 0.f : cbuf[(size_t)m * 64 + cc];
        c = hsig(zf) * c + hsig(zi) * tanhf(zg);
        float h = hsig(zo) * tanhf(c);
        cbuf[(size_t)m * 64 + cc] = c;
        stacked[(size_t)m * 768 + t * 64 + cc] = __float2bfloat16(h);
    }
}

// ---------------------------------------------------------------------------
// compconv MFMA: comp = relu(stacked[4608,768] @ wo + bo) -> bf16 [4608,64]
// Block: 4 waves x 16 rows = 64 rows, each wave covers all N=64.
// ---------------------------------------------------------------------------
__global__ __launch_bounds__(256) void compconv_mfma(
    const __hip_bfloat16* __restrict__ stacked,
    const __hip_bfloat16* __restrict__ woP,
    const float* __restrict__ bo,
    __hip_bfloat16* __restrict__ comp)
{
    const int tid = threadIdx.x;
    const int l = tid & 63, w = tid >> 6;
    const int cl = l & 15, q = l >> 4;
    const int m0 = blockIdx.x * 64 + w * 16;
    const __bf16* st = reinterpret_cast<const __bf16*>(stacked);
    const __bf16* wp = reinterpret_cast<const __bf16*>(woP);

    f32x4 acc[4];
    #pragma unroll
    for (int nj = 0; nj < 4; nj++) acc[nj] = (f32x4){0.f, 0.f, 0.f, 0.f};

    for (int ks = 0; ks < 24; ks++) {
        v8bf a = *reinterpret_cast<const v8bf*>(&st[(size_t)(m0 + cl) * 768 + ks * 32 + q * 8]);
        #pragma unroll
        for (int nj = 0; nj < 4; nj++) {
            v8bf b = *reinterpret_cast<const v8bf*>(&wp[(size_t)((nj * 24 + ks) * 64 + l) * 8]);
            acc[nj] = __builtin_amdgcn_mfma_f32_16x16x32_bf16(a, b, acc[nj], 0, 0, 0);
        }
    }
    __bf16* cp = reinterpret_cast<__bf16*>(comp);
    #pragma unroll
    for (int nj = 0; nj < 4; nj++) {
        int c = nj * 16 + cl;
        float bias = bo[c];
        #pragma unroll
        for (int reg = 0; reg < 4; reg++) {
            int m = m0 + q * 4 + reg;
            cp[(size_t)m * 64 + c] = (__bf16)fmaxf(acc[nj][reg] + bias, 0.f);
        }
    }
}

// ---------------------------------------------------------------------------
// dense1 MFMA: hdn = relu(comp[32,9216]bf16 @ wd1 + bd1) -> f32 [32,128]
// 8 blocks (one per 16-col group); 4 waves split K; LDS reduce.
// ---------------------------------------------------------------------------
__global__ __launch_bounds__(256) void dense1_mfma(
    const __hip_bfloat16* __restrict__ comp,
    const __hip_bfloat16* __restrict__ wd1P,
    const float* __restrict__ bd1,
    float* __restrict__ hdn)
{
    __shared__ float red[4][32][16];
    const int tid = threadIdx.x;
    const int l = tid & 63, w = tid >> 6;
    const int cl = l & 15, q = l >> 4;
    const int g = blockIdx.x;                 // 0..7
    const __bf16* cpp = reinterpret_cast<const __bf16*>(comp);
    const __bf16* wpp = reinterpret_cast<const __bf16*>(wd1P) + (size_t)g * 288 * 512;

    f32x4 acc[2];
    acc[0] = (f32x4){0.f, 0.f, 0.f, 0.f};
    acc[1] = (f32x4){0.f, 0.f, 0.f, 0.f};

    for (int ks = w * 72; ks < w * 72 + 72; ks++) {
        v8bf b = *reinterpret_cast<const v8bf*>(&wpp[(size_t)ks * 512 + l * 8]);
        #pragma unroll
        for (int mi = 0; mi < 2; mi++) {
            v8bf a = *reinterpret_cast<const v8bf*>(
                &cpp[(size_t)(mi * 16 + cl) * 9216 + ks * 32 + q * 8]);
            acc[mi] = __builtin_amdgcn_mfma_f32_16x16x32_bf16(a, b, acc[mi], 0, 0, 0);
        }
    }
    #pragma unroll
    for (int mi = 0; mi < 2; mi++)
        #pragma unroll
        for (int reg = 0; reg < 4; reg++)
            red[w][mi * 16 + q * 4 + reg][cl] = acc[mi][reg];
    __syncthreads();

    for (int i = tid; i < 512; i += 256) {
        int row = i >> 4, c = i & 15;
        float s = red[0][row][c] + red[1][row][c] + red[2][row][c] + red[3][row][c];
        int col = g * 16 + c;
        hdn[row * 128 + col] = fmaxf(s + bd1[col], 0.f);
    }
}

// ---------------------------------------------------------------------------
// dense2 + softmax
// ---------------------------------------------------------------------------
__global__ void dense2_k(const float* __restrict__ hdn,
                         const float* __restrict__ wd2,
                         const float* __restrict__ bd2,
                         float* __restrict__ out)
{
    int r = threadIdx.x;
    if (r >= 32) return;
    float l0 = bd2[0], l1 = bd2[1];
    for (int k = 0; k < 128; k++) {
        float h = hdn[r * 128 + k];
        l0 = fmaf(h, wd2[k * 2 + 0], l0);
        l1 = fmaf(h, wd2[k * 2 + 1], l1);
    }
    float mx = fmaxf(l0, l1);
    float e0 = expf(l0 - mx), e1 = expf(l1 - mx);
    float s = e0 + e1;
    out[r * 2 + 0] = e0 / s;
    out[r * 2 + 1] = e1 / s;
}

// ---------------------------------------------------------------------------

extern "C" void kernel_launch(void* const* d_in, const int* in_sizes, int n_in,
                              void* d_out, int out_size, void* d_ws, size_t ws_size,
                              hipStream_t stream)
{
    const float* img   = (const float*)d_in[0];
    const float* bn0g  = (const float*)d_in[1];
    const float* bn0b  = (const float*)d_in[2];
    const float* bn0m  = (const float*)d_in[3];
    const float* bn0v  = (const float*)d_in[4];
    const float* w1    = (const float*)d_in[5];
    const float* b1    = (const float*)d_in[6];
    const float* bn1g  = (const float*)d_in[7];
    const float* bn1b  = (const float*)d_in[8];
    const float* bn1m  = (const float*)d_in[9];
    const float* bn1v  = (const float*)d_in[10];
    const float* w2    = (const float*)d_in[11];
    const float* b2    = (const float*)d_in[12];
    const float* bn2g  = (const float*)d_in[13];
    const float* bn2b  = (const float*)d_in[14];
    const float* bn2m  = (const float*)d_in[15];
    const float* bn2v  = (const float*)d_in[16];
    const float* wx    = (const float*)d_in[17];
    const float* wh    = (const float*)d_in[18];
    const float* blstm = (const float*)d_in[19];
    const float* wo    = (const float*)d_in[20];
    const float* bo    = (const float*)d_in[21];
    const float* wd1   = (const float*)d_in[22];
    const float* bd1   = (const float*)d_in[23];
    const float* wd2   = (const float*)d_in[24];
    const float* bd2   = (const float*)d_in[25];
    float* out = (float*)d_out;

    float* ws = (float*)d_ws;
    size_t o = 0;
    float* w1f = ws + o; o += 1024;
    float* b1f = ws + o; o += 16;
    float* w2f = ws + o; o += 4608;
    float* b2f = ws + o; o += 32;
    float* blf = ws + o; o += 256;
    __hip_bfloat16* wxfP = (__hip_bfloat16*)(ws + o); o += 65536;     // 131072 bf16
    __hip_bfloat16* whP  = (__hip_bfloat16*)(ws + o); o += 131072;    // 262144 bf16
    __hip_bfloat16* woP  = (__hip_bfloat16*)(ws + o); o += 24576;     // 49152 bf16
    __hip_bfloat16* wd1P = (__hip_bfloat16*)(ws + o); o += 589824;    // 1179648 bf16
    __hip_bfloat16* act2 = (__hip_bfloat16*)(ws + o); o += 1382400;   // 2764800 bf16
    __hip_bfloat16* stacked = (__hip_bfloat16*)(ws + o); o += 1769472; // 3538944 bf16
    float* cbuf = ws + o; o += 294912;
    __hip_bfloat16* comp = (__hip_bfloat16*)(ws + o); o += 147456;    // 294912 bf16
    float* hdn  = ws + o; o += 4096;
    float* act1 = ws + o;                    // union: act1 [384,31,31,16] f32
    float* zx   = ws + o; o += 14155776;     // zx [384,144,256] f32 (act1 dead)

    fold_weights<<<(1627952 + 255) / 256, 256, 0, stream>>>(
        bn0g, bn0b, bn0m, bn0v, w1, b1,
        bn1g, bn1b, bn1m, bn1v, w2, b2,
        bn2g, bn2b, bn2m, bn2v, wx, wh, blstm, wo, wd1,
        w1f, b1f, w2f, b2f, wxfP, whP, woP, wd1P, blf);

    conv1_k<<<(384 * 961 + 255) / 256, 256, 0, stream>>>(img, w1f, b1f, act1);
    conv2_k<<<(384 * 225 + 255) / 256, 256, 0, stream>>>(act1, w2f, b2f, act2);
    xconv_mfma<<<(384 * 144) / XBM, 256, 0, stream>>>(act2, wxfP, blf, zx);

    for (int t = 0; t < 12; t++)
        lstm_mfma<<<(32 * 144) / LBM, 256, 0, stream>>>(zx, whP, stacked, cbuf, t);

    compconv_mfma<<<4608 / 64, 256, 0, stream>>>(stacked, woP, bo, comp);
    dense1_mfma<<<8, 256, 0, stream>>>(comp, wd1P, bd1, hdn);
    dense2_k<<<1, 64, 0, stream>>>(hdn, wd2, bd2, out);
}